// Round 11
// baseline (610.079 us; speedup 1.0000x reference)
//
#include <hip/hip_runtime.h>
#include <math.h>

#define REGC 1e-6f
#define LOG2PI 1.83787706640934534f
#define RESP_EPS 1.1920929e-6f

#define SK 1156                     // per-component S stride (34x34 used: 1121)

typedef __attribute__((ext_vector_type(8))) short short8;
typedef __attribute__((ext_vector_type(4))) float f32x4;
typedef unsigned short ushort_t;
typedef unsigned int uint_t;

__device__ __forceinline__ ushort_t f2bf(float x) {
    uint_t u = __float_as_uint(x);
    uint_t r = (u + 0x7fffu + ((u >> 16) & 1u)) >> 16;   // RNE
    return (ushort_t)r;
}
__device__ __forceinline__ float bf2f(ushort_t h) {
    return __uint_as_float(((uint_t)h) << 16);
}
__device__ __forceinline__ f32x4 shx4(f32x4 v, int m) {
    f32x4 r;
#pragma unroll
    for (int i = 0; i < 4; ++i) r[i] = __shfl_xor(v[i], m);
    return r;
}
__device__ __forceinline__ f32x4 sel4(bool s, f32x4 b, f32x4 a) {
    f32x4 r;
#pragma unroll
    for (int i = 0; i < 4; ++i) r[i] = s ? b[i] : a[i];
    return r;
}
// r*x -> bf16 (round-half-up) packed A-frag; accumulates row sum.
// 1 v_add per elt + 1 v_perm per pair (vs ~5 inst RNE f2bf).
__device__ __forceinline__ short8 pack_rx(const float* r8, const short8 bh, float& row) {
    uint_t u[8];
#pragma unroll
    for (int jj = 0; jj < 8; ++jj) {
        float av = r8[jj] * bf2f((ushort_t)bh[jj]);
        row += av;
        u[jj] = __float_as_uint(av) + 0x8000u;
    }
    short8 out;
    uint_t* o = (uint_t*)&out;
    o[0] = __builtin_amdgcn_perm(u[1], u[0], 0x07060302);
    o[1] = __builtin_amdgcn_perm(u[3], u[2], 0x07060302);
    o[2] = __builtin_amdgcn_perm(u[5], u[4], 0x07060302);
    o[3] = __builtin_amdgcn_perm(u[7], u[6], 0x07060302);
    return out;
}

// ---------------- xsplit: row-major Xh/Xl (estep) + frag-layout XTH (moment) ----
__global__ __launch_bounds__(256) void gmm_xsplit(const float* __restrict__ X,
                                                  ushort_t* __restrict__ Xh,
                                                  ushort_t* __restrict__ Xl,
                                                  ushort_t* __restrict__ XTH,
                                                  int N) {
    int chunk = blockIdx.x;
    int t = threadIdx.x;
    __shared__ float xsh[32][33];
    int s = t >> 3, q = t & 7;
    int n = chunk * 32 + s;
    float4 v = make_float4(0.f, 0.f, 0.f, 0.f);
    if (n < N) v = ((const float4*)(X + (size_t)n * 32))[q];
    float vv[4] = { v.x, v.y, v.z, v.w };
    xsh[s][q * 4 + 0] = v.x; xsh[s][q * 4 + 1] = v.y;
    xsh[s][q * 4 + 2] = v.z; xsh[s][q * 4 + 3] = v.w;
    if (n < N) {
        ushort_t h[4], l[4];
#pragma unroll
        for (int i = 0; i < 4; ++i) {
            h[i] = f2bf(vv[i]);
            l[i] = f2bf(vv[i] - bf2f(h[i]));
        }
        size_t o = (size_t)n * 32 + q * 4;
        *(uint2*)(Xh + o) = make_uint2((uint_t)h[0] | ((uint_t)h[1] << 16),
                                       (uint_t)h[2] | ((uint_t)h[3] << 16));
        *(uint2*)(Xl + o) = make_uint2((uint_t)l[0] | ((uint_t)l[1] << 16),
                                       (uint_t)l[2] | ((uint_t)l[3] << 16));
    }
    __syncthreads();
    int di = t >> 7;
    int lane = (t >> 1) & 63;
    int jj0 = (t & 1) * 4;
    int c = lane & 15, quad = lane >> 4;
    int d = di * 16 + c;
    ushort_t fh[4];
#pragma unroll
    for (int i = 0; i < 4; ++i) fh[i] = f2bf(xsh[quad * 8 + jj0 + i][d]);
    size_t fo = ((size_t)(chunk * 2 + di) * 64 + lane) * 8 + jj0;
    *(uint2*)(XTH + fo) = make_uint2((uint_t)fh[0] | ((uint_t)fh[1] << 16),
                                     (uint_t)fh[2] | ((uint_t)fh[3] << 16));
}

// ---------------- prep0: raw inputs -> W/Bv/Cc; zeroes S for iteration 0 ----
__global__ __launch_bounds__(64) void gmm_prep0(const float* __restrict__ w,
                                                const float* __restrict__ mu,
                                                const float* __restrict__ cov,
                                                ushort_t* __restrict__ Wh,
                                                ushort_t* __restrict__ Wl,
                                                float* __restrict__ Bv,
                                                float* __restrict__ Cc,
                                                float* __restrict__ S) {
    int k = blockIdx.x;
    int t = threadIdx.x;
    __shared__ float L[32][33];
    __shared__ float Ai[32][33];
    const float* cv = cov + (size_t)k * 1024;
    const float* muk = mu + (size_t)k * 32;
    for (int idx = t; idx < SK; idx += 64) S[k * SK + idx] = 0.f;
#pragma unroll
    for (int rep = 0; rep < 16; ++rep) {
        int idx = rep * 64 + t;
        int i = idx >> 5, j = idx & 31;
        L[i][j] = cv[idx] + (i == j ? REGC : 0.f);
    }
    __syncthreads();
#pragma unroll
    for (int j = 0; j < 32; ++j) {
        float s = L[j][j];
#pragma unroll
        for (int p = 0; p < j; ++p) { float v = L[j][p]; s -= v * v; }
        float dj = sqrtf(s);
        if (t > j && t < 32) {
            float s2 = L[t][j];
#pragma unroll
            for (int p = 0; p < j; ++p) s2 -= L[t][p] * L[j][p];
            L[t][j] = s2 / dj;
        }
        if (t == j) L[j][j] = dj;
        __syncthreads();
    }
    if (t < 32) {
        float ai[32];
#pragma unroll
        for (int r = 0; r < 32; ++r) {
            float s = (r == t) ? 1.f : 0.f;
#pragma unroll
            for (int p = 0; p < r; ++p) s -= L[r][p] * ai[p];
            ai[r] = s / L[r][r];
        }
#pragma unroll
        for (int r = 0; r < 32; ++r) Ai[r][t] = ai[r];
    }
    __syncthreads();
#pragma unroll
    for (int rep = 0; rep < 16; ++rep) {
        int idx = rep * 64 + t;
        int i = idx >> 5, j = idx & 31;
        float v = Ai[i][j];
        ushort_t h = f2bf(v);
        Wh[(size_t)(k * 32 + i) * 32 + j] = h;
        Wl[(size_t)(k * 32 + i) * 32 + j] = f2bf(v - bf2f(h));
    }
    if (t < 32) {
        float s = 0.f;
#pragma unroll
        for (int j = 0; j < 32; ++j) s += Ai[t][j] * muk[j];
        Bv[k * 32 + t] = s;
    }
    float wsum = 0.f;
#pragma unroll
    for (int i = 0; i < 16; ++i) wsum += w[i];
    float lv = (t < 32) ? logf(L[t & 31][t & 31]) : 0.f;
#pragma unroll
    for (int off = 1; off < 32; off <<= 1) lv += __shfl_xor(lv, off);
    if (t == 0) Cc[k] = logf(w[k] / wsum) - 0.5f * 32.0f * LOG2PI - lv;
}

// ---------------- fused estep+moment: 512 thr = 8 waves, 256 samples/block ---------
// Phase 1: wave = 1 chunk (32 samples), validated MFMA estep + merged butterfly,
// resp -> LDS. Phase 2: wave handles comps {w, w+8} sequentially (16-VGPR accums,
// stays <=64 VGPR -> 8 waves/EU). Moment accumulated via device-scope atomicAdd
// into the L2-resident S[16][SK] (replaces partials + reduce1 kernel).
__global__ __launch_bounds__(512)
void gmm_emstep(const ushort_t* __restrict__ Xh, const ushort_t* __restrict__ Xl,
                const ushort_t* __restrict__ XTH,
                const ushort_t* __restrict__ Wh, const ushort_t* __restrict__ Wl,
                const float* __restrict__ Bv, const float* __restrict__ Cc,
                float* __restrict__ S, int N) {
    __shared__ float rsh[16][260];
    int t = threadIdx.x;
    int wave = t >> 6, lane = t & 63;
    int quad = lane >> 4, c = lane & 15;

    int wstart0 = (int)blockIdx.x * 256 + wave * 32;
    bool dup = (wstart0 + 32 > N);
    int wst = dup ? ((N >= 32) ? N - 32 : 0) : wstart0;

    size_t xo0 = (size_t)(wst + c) * 32 + quad * 8;
    size_t xo1 = (size_t)(wst + 16 + c) * 32 + quad * 8;
    short8 ah0 = *(const short8*)(Xh + xo0);
    short8 al0 = *(const short8*)(Xl + xo0);
    short8 ah1 = *(const short8*)(Xh + xo1);
    short8 al1 = *(const short8*)(Xl + xo1);

    // ---- phase 1: estep (R4-R10-validated) ----
    {
        f32x4 p0[2], p1[2], p2[2], p3[2], fin[2];
#pragma unroll
        for (int k = 0; k < 16; ++k) {
            size_t w0 = (size_t)(k * 32 + c) * 32 + quad * 8;
            size_t w1 = w0 + 512;
            short8 bh0 = *(const short8*)(Wh + w0);
            short8 bl0 = *(const short8*)(Wl + w0);
            short8 bh1 = *(const short8*)(Wh + w1);
            short8 bl1 = *(const short8*)(Wl + w1);
            float bv0 = Bv[k * 32 + c];
            float bv1 = Bv[k * 32 + 16 + c];
#pragma unroll
            for (int tt = 0; tt < 2; ++tt) {
                short8 ah = tt ? ah1 : ah0;
                short8 al = tt ? al1 : al0;
                f32x4 a0 = {0.f, 0.f, 0.f, 0.f};
                f32x4 a1 = {0.f, 0.f, 0.f, 0.f};
                a0 = __builtin_amdgcn_mfma_f32_16x16x32_bf16(ah, bh0, a0, 0, 0, 0);
                a0 = __builtin_amdgcn_mfma_f32_16x16x32_bf16(ah, bl0, a0, 0, 0, 0);
                a0 = __builtin_amdgcn_mfma_f32_16x16x32_bf16(al, bh0, a0, 0, 0, 0);
                a1 = __builtin_amdgcn_mfma_f32_16x16x32_bf16(ah, bh1, a1, 0, 0, 0);
                a1 = __builtin_amdgcn_mfma_f32_16x16x32_bf16(ah, bl1, a1, 0, 0, 0);
                a1 = __builtin_amdgcn_mfma_f32_16x16x32_bf16(al, bh1, a1, 0, 0, 0);
                f32x4 ms;
#pragma unroll
                for (int r = 0; r < 4; ++r) {
                    float d0 = a0[r] - bv0;
                    float d1 = a1[r] - bv1;
                    ms[r] = fmaf(d0, d0, d1 * d1);
                }
                if ((k & 1) == 0) { p0[tt] = ms; }
                else {
                    f32x4 a = p0[tt] + shx4(p0[tt], 1);
                    f32x4 b = ms + shx4(ms, 1);
                    f32x4 v = sel4((c & 1) != 0, b, a);
                    if ((k & 2) == 0) { p1[tt] = v; }
                    else {
                        a = p1[tt] + shx4(p1[tt], 2); b = v + shx4(v, 2); v = sel4((c & 2) != 0, b, a);
                        if ((k & 4) == 0) { p2[tt] = v; }
                        else {
                            a = p2[tt] + shx4(p2[tt], 4); b = v + shx4(v, 4); v = sel4((c & 4) != 0, b, a);
                            if ((k & 8) == 0) { p3[tt] = v; }
                            else {
                                a = p3[tt] + shx4(p3[tt], 8); b = v + shx4(v, 8);
                                fin[tt] = sel4((c & 8) != 0, b, a);
                            }
                        }
                    }
                }
            }
        }
        float ccv = Cc[c];
#pragma unroll
        for (int tt = 0; tt < 2; ++tt) {
            f32x4 lp;
#pragma unroll
            for (int r = 0; r < 4; ++r) lp[r] = ccv - 0.5f * fin[tt][r];
            f32x4 mx = lp;
#pragma unroll
            for (int off = 1; off < 16; off <<= 1) {
                f32x4 s = shx4(mx, off);
#pragma unroll
                for (int r = 0; r < 4; ++r) mx[r] = fmaxf(mx[r], s[r]);
            }
            f32x4 e;
#pragma unroll
            for (int r = 0; r < 4; ++r) e[r] = __expf(lp[r] - mx[r]);
            f32x4 sm = e;
#pragma unroll
            for (int off = 1; off < 16; off <<= 1) sm = sm + shx4(sm, off);
            f32x4 sv;
#pragma unroll
            for (int r = 0; r < 4; ++r) sv[r] = dup ? 0.f : e[r] / sm[r];
            *(f32x4*)&rsh[c][wave * 32 + tt * 16 + quad * 4] = sv;
        }
    }
    __syncthreads();

    // ---- phase 2: moment, comps {wave, wave+8} sequentially ----
#pragma unroll 1
    for (int kk = 0; kk < 2; ++kk) {
        int k = wave + kk * 8;
        f32x4 m00 = {0.f,0.f,0.f,0.f}, m01 = {0.f,0.f,0.f,0.f};
        f32x4 m10 = {0.f,0.f,0.f,0.f}, m11 = {0.f,0.f,0.f,0.f};
        float row0 = 0.f, row1 = 0.f, corner = 0.f;
#pragma unroll 2
        for (int ch = 0; ch < 8; ++ch) {
            size_t chunk = (size_t)blockIdx.x * 8 + ch;
            size_t fb = (chunk * 128 + lane) * 8;
            short8 bh0 = *(const short8*)(XTH + fb);
            short8 bh1 = *(const short8*)(XTH + fb + 512);
            const float* rp = &rsh[k][ch * 32 + quad * 8];
            float r8[8];
#pragma unroll
            for (int jj = 0; jj < 8; ++jj) r8[jj] = rp[jj];
            corner += ((r8[0]+r8[1])+(r8[2]+r8[3])) + ((r8[4]+r8[5])+(r8[6]+r8[7]));
            short8 a0 = pack_rx(r8, bh0, row0);
            short8 a1 = pack_rx(r8, bh1, row1);
            m00 = __builtin_amdgcn_mfma_f32_16x16x32_bf16(a0, bh0, m00, 0, 0, 0);
            m01 = __builtin_amdgcn_mfma_f32_16x16x32_bf16(a0, bh1, m01, 0, 0, 0);
            m10 = __builtin_amdgcn_mfma_f32_16x16x32_bf16(a1, bh0, m10, 0, 0, 0);
            m11 = __builtin_amdgcn_mfma_f32_16x16x32_bf16(a1, bh1, m11, 0, 0, 0);
        }
        row0 += __shfl_xor(row0, 16);  row0 += __shfl_xor(row0, 32);
        row1 += __shfl_xor(row1, 16);  row1 += __shfl_xor(row1, 32);
        corner += __shfl_xor(corner, 16);  corner += __shfl_xor(corner, 32);

        float* Sk = S + k * SK;
#pragma unroll
        for (int r = 0; r < 4; ++r) {
            atomicAdd(&Sk[(quad * 4 + r) * 34 + c],           m00[r]);
            atomicAdd(&Sk[(quad * 4 + r) * 34 + 16 + c],      m01[r]);
            atomicAdd(&Sk[(16 + quad * 4 + r) * 34 + c],      m10[r]);
            atomicAdd(&Sk[(16 + quad * 4 + r) * 34 + 16 + c], m11[r]);
        }
        if (quad == 0) {
            atomicAdd(&Sk[32 * 34 + c],      row0);
            atomicAdd(&Sk[32 * 34 + 16 + c], row1);
        }
        if (lane == 0) atomicAdd(&Sk[32 * 34 + 32], corner);
    }
}

// ---------------- finalize + prep from S; re-zeroes S for next iteration ---------
__global__ __launch_bounds__(1024) void gmm_redfin_prep(float* __restrict__ Sg,
                                                        ushort_t* __restrict__ Wh,
                                                        ushort_t* __restrict__ Wl,
                                                        float* __restrict__ Bv,
                                                        float* __restrict__ Cc,
                                                        int N) {
    int k = blockIdx.x;
    int t = threadIdx.x;
    __shared__ float S[1156];
    __shared__ float L[1056];     // 32x33
    __shared__ float Ai[1056];
    __shared__ float mean[32];

    for (int idx = t; idx < 1156; idx += 1024) {
        S[idx] = Sg[k * SK + idx];
        Sg[k * SK + idx] = 0.f;    // same thread read-then-zero: no hazard
    }
    __syncthreads();
    float nk = S[32 * 34 + 32] + RESP_EPS;
    float inv = 1.f / nk;
    {
        int i = t >> 5, j = t & 31;
        float mi = S[32 * 34 + i] * inv;
        float mj = S[32 * 34 + j] * inv;
        // M-step REGC + log_gauss REGC (reference applies both)
        L[i * 33 + j] = S[i * 34 + j] * inv - mi * mj + ((i == j) ? 2.f * REGC : 0.f);
    }
    if (t < 32) mean[t] = S[32 * 34 + t] * inv;
    __syncthreads();

#pragma unroll
    for (int j = 0; j < 32; ++j) {
        if (t < 32) {
            float s = L[j * 33 + j];
#pragma unroll
            for (int p = 0; p < j; ++p) { float v = L[j * 33 + p]; s -= v * v; }
            float dj = sqrtf(s);
            if (t > j) {
                float s2 = L[t * 33 + j];
#pragma unroll
                for (int p = 0; p < j; ++p) s2 -= L[t * 33 + p] * L[j * 33 + p];
                L[t * 33 + j] = s2 / dj;
            }
            if (t == j) L[j * 33 + j] = dj;
        }
        __syncthreads();
    }
    if (t < 32) {
        float ai[32];
#pragma unroll
        for (int r = 0; r < 32; ++r) {
            float s = (r == t) ? 1.f : 0.f;
#pragma unroll
            for (int p = 0; p < r; ++p) s -= L[r * 33 + p] * ai[p];
            ai[r] = s / L[r * 33 + r];
        }
#pragma unroll
        for (int r = 0; r < 32; ++r) Ai[r * 33 + t] = ai[r];
    }
    __syncthreads();
    {
        int i = t >> 5, j = t & 31;
        float v = Ai[i * 33 + j];
        ushort_t h = f2bf(v);
        Wh[(size_t)(k * 32 + i) * 32 + j] = h;
        Wl[(size_t)(k * 32 + i) * 32 + j] = f2bf(v - bf2f(h));
    }
    if (t < 32) {
        float s = 0.f;
#pragma unroll
        for (int j = 0; j < 32; ++j) s += Ai[t * 33 + j] * mean[j];
        Bv[k * 32 + t] = s;
    }
    float lv = (t < 32) ? logf(L[(t & 31) * 33 + (t & 31)]) : 0.f;
#pragma unroll
    for (int off = 1; off < 32; off <<= 1) lv += __shfl_xor(lv, off);
    if (t == 0) Cc[k] = logf(nk / (float)N) - 0.5f * 32.0f * LOG2PI - lv;
}

// ---------------- final estep: log-likelihood only (R7-R10-validated) --------------
__global__ __launch_bounds__(256, 2) void gmm_estep_fin(const ushort_t* __restrict__ Xh,
                                                        const ushort_t* __restrict__ Xl,
                                                        const ushort_t* __restrict__ Wh,
                                                        const ushort_t* __restrict__ Wl,
                                                        const float* __restrict__ Bv,
                                                        const float* __restrict__ Cc,
                                                        float* __restrict__ out,
                                                        int N) {
    int t = threadIdx.x;
    int wave = t >> 6, lane = t & 63;
    int quad = lane >> 4, c = lane & 15;
    int wstart = (blockIdx.x * 4 + wave) * 32;
    if (wstart + 32 > N) wstart = (N >= 32) ? (N - 32) : 0;
    bool al4 = ((N & 3) == 0);

    size_t xo0 = (size_t)(wstart + c) * 32 + quad * 8;
    size_t xo1 = (size_t)(wstart + 16 + c) * 32 + quad * 8;
    short8 ah0 = *(const short8*)(Xh + xo0);
    short8 al0 = *(const short8*)(Xl + xo0);
    short8 ah1 = *(const short8*)(Xh + xo1);
    short8 al1 = *(const short8*)(Xl + xo1);

    f32x4 p0[2], p1[2], p2[2], p3[2], fin[2];
#pragma unroll
    for (int k = 0; k < 16; ++k) {
        size_t w0 = (size_t)(k * 32 + c) * 32 + quad * 8;
        size_t w1 = w0 + 512;
        short8 bh0 = *(const short8*)(Wh + w0);
        short8 bl0 = *(const short8*)(Wl + w0);
        short8 bh1 = *(const short8*)(Wh + w1);
        short8 bl1 = *(const short8*)(Wl + w1);
        float bv0 = Bv[k * 32 + c];
        float bv1 = Bv[k * 32 + 16 + c];
#pragma unroll
        for (int tt = 0; tt < 2; ++tt) {
            short8 ah = tt ? ah1 : ah0;
            short8 al = tt ? al1 : al0;
            f32x4 a0 = {0.f, 0.f, 0.f, 0.f};
            f32x4 a1 = {0.f, 0.f, 0.f, 0.f};
            a0 = __builtin_amdgcn_mfma_f32_16x16x32_bf16(ah, bh0, a0, 0, 0, 0);
            a0 = __builtin_amdgcn_mfma_f32_16x16x32_bf16(ah, bl0, a0, 0, 0, 0);
            a0 = __builtin_amdgcn_mfma_f32_16x16x32_bf16(al, bh0, a0, 0, 0, 0);
            a1 = __builtin_amdgcn_mfma_f32_16x16x32_bf16(ah, bh1, a1, 0, 0, 0);
            a1 = __builtin_amdgcn_mfma_f32_16x16x32_bf16(ah, bl1, a1, 0, 0, 0);
            a1 = __builtin_amdgcn_mfma_f32_16x16x32_bf16(al, bh1, a1, 0, 0, 0);
            f32x4 ms;
#pragma unroll
            for (int r = 0; r < 4; ++r) {
                float d0 = a0[r] - bv0;
                float d1 = a1[r] - bv1;
                ms[r] = fmaf(d0, d0, d1 * d1);
            }
            if ((k & 1) == 0) { p0[tt] = ms; }
            else {
                f32x4 a = p0[tt] + shx4(p0[tt], 1);
                f32x4 b = ms + shx4(ms, 1);
                f32x4 v = sel4((c & 1) != 0, b, a);
                if ((k & 2) == 0) { p1[tt] = v; }
                else {
                    a = p1[tt] + shx4(p1[tt], 2); b = v + shx4(v, 2); v = sel4((c & 2) != 0, b, a);
                    if ((k & 4) == 0) { p2[tt] = v; }
                    else {
                        a = p2[tt] + shx4(p2[tt], 4); b = v + shx4(v, 4); v = sel4((c & 4) != 0, b, a);
                        if ((k & 8) == 0) { p3[tt] = v; }
                        else {
                            a = p3[tt] + shx4(p3[tt], 8); b = v + shx4(v, 8);
                            fin[tt] = sel4((c & 8) != 0, b, a);
                        }
                    }
                }
            }
        }
    }
    float ccv = Cc[c];
#pragma unroll
    for (int tt = 0; tt < 2; ++tt) {
        f32x4 lp;
#pragma unroll
        for (int r = 0; r < 4; ++r) lp[r] = ccv - 0.5f * fin[tt][r];
        f32x4 mx = lp;
#pragma unroll
        for (int off = 1; off < 16; off <<= 1) {
            f32x4 s = shx4(mx, off);
#pragma unroll
            for (int r = 0; r < 4; ++r) mx[r] = fmaxf(mx[r], s[r]);
        }
        f32x4 e;
#pragma unroll
        for (int r = 0; r < 4; ++r) e[r] = __expf(lp[r] - mx[r]);
        f32x4 sm = e;
#pragma unroll
        for (int off = 1; off < 16; off <<= 1) sm = sm + shx4(sm, off);
        if (c == 0) {
            int nb = wstart + tt * 16 + quad * 4;
            f32x4 o;
#pragma unroll
            for (int r = 0; r < 4; ++r) o[r] = mx[r] + __logf(sm[r]);
            if (al4) *(f32x4*)(out + nb) = o;
            else { for (int r = 0; r < 4; ++r) out[nb + r] = o[r]; }
        }
    }
}

// ================================== launcher ==================================
extern "C" void kernel_launch(void* const* d_in, const int* in_sizes, int n_in,
                              void* d_out, int out_size, void* d_ws, size_t ws_size,
                              hipStream_t stream) {
    const float* X   = (const float*)d_in[0];
    const float* w   = (const float*)d_in[1];
    const float* mu  = (const float*)d_in[2];
    const float* cov = (const float*)d_in[3];
    const int NITER = 5;
    int N = in_sizes[0] / 32;
    int NB = (N + 255) / 256;        // emstep blocks (256 samples each)
    int NCB = NB * 8;                // staged chunks (zero-padded past N)

    float* ws = (float*)d_ws;
    float*    Bv = ws;                               // 512
    float*    Cc = ws + 512;                         // 16 (+pad to 528)
    ushort_t* Wh = (ushort_t*)(ws + 528);            // 8192 f
    ushort_t* Wl = (ushort_t*)(ws + 8720);           // 8192 f -> 16912
    ushort_t* Xh = (ushort_t*)(ws + 16912);          // 16N f
    ushort_t* Xl = (ushort_t*)(ws + 16912 + (size_t)16 * N);
    size_t xt0 = 16912 + (size_t)32 * N;
    size_t SZ  = (size_t)NCB * 512;                  // XTH floats
    ushort_t* XTH = (ushort_t*)(ws + xt0);
    float*  S  = ws + xt0 + SZ;                      // 16*SK floats (L2-resident)

    float* out = (float*)d_out;

    int eblocks = ((N + 31) / 32 + 3) / 4;

    gmm_xsplit<<<NCB, 256, 0, stream>>>(X, Xh, Xl, XTH, N);
    gmm_prep0<<<16, 64, 0, stream>>>(w, mu, cov, Wh, Wl, Bv, Cc, S);

    for (int it = 0; it < NITER; ++it) {
        gmm_emstep<<<NB, 512, 0, stream>>>(Xh, Xl, XTH, Wh, Wl, Bv, Cc, S, N);
        gmm_redfin_prep<<<16, 1024, 0, stream>>>(S, Wh, Wl, Bv, Cc, N);
    }
    gmm_estep_fin<<<eblocks, 256, 0, stream>>>(Xh, Xl, Wh, Wl, Bv, Cc, out, N);
}

// Round 12
// 454.987 us; speedup vs baseline: 1.3409x; 1.3409x over previous
//
#include <hip/hip_runtime.h>
#include <math.h>

#define REGC 1e-6f
#define LOG2PI 1.83787706640934534f
#define RESP_EPS 1.1920929e-6f

#define PART_K 1156                 // 34x34 per (block,k) partial
#define RS 16                       // reduce stage-1 slices

typedef __attribute__((ext_vector_type(8))) short short8;
typedef __attribute__((ext_vector_type(4))) float f32x4;
typedef unsigned short ushort_t;
typedef unsigned int uint_t;

__device__ __forceinline__ ushort_t f2bf(float x) {
    uint_t u = __float_as_uint(x);
    uint_t r = (u + 0x7fffu + ((u >> 16) & 1u)) >> 16;   // RNE
    return (ushort_t)r;
}
__device__ __forceinline__ float bf2f(ushort_t h) {
    return __uint_as_float(((uint_t)h) << 16);
}
__device__ __forceinline__ f32x4 shx4(f32x4 v, int m) {
    f32x4 r;
#pragma unroll
    for (int i = 0; i < 4; ++i) r[i] = __shfl_xor(v[i], m);
    return r;
}
__device__ __forceinline__ f32x4 sel4(bool s, f32x4 b, f32x4 a) {
    f32x4 r;
#pragma unroll
    for (int i = 0; i < 4; ++i) r[i] = s ? b[i] : a[i];
    return r;
}
// r*x -> bf16 (round-half-up) packed A-frag; accumulates row sum.
// ~3.5 inst/elt (mul+fma+add + perm/2) vs ~6 for RNE f2bf.
__device__ __forceinline__ short8 pack_rx(const float* r8, const short8 bh, float& row) {
    uint_t u[8];
#pragma unroll
    for (int jj = 0; jj < 8; ++jj) {
        float av = r8[jj] * bf2f((ushort_t)bh[jj]);
        row += av;
        u[jj] = __float_as_uint(av) + 0x8000u;
    }
    short8 out;
    uint_t* o = (uint_t*)&out;
    o[0] = __builtin_amdgcn_perm(u[1], u[0], 0x07060302);
    o[1] = __builtin_amdgcn_perm(u[3], u[2], 0x07060302);
    o[2] = __builtin_amdgcn_perm(u[5], u[4], 0x07060302);
    o[3] = __builtin_amdgcn_perm(u[7], u[6], 0x07060302);
    return out;
}

// ---------------- xsplit: row-major Xh/Xl (estep) + frag-layout XTH (moment) ----
__global__ __launch_bounds__(256) void gmm_xsplit(const float* __restrict__ X,
                                                  ushort_t* __restrict__ Xh,
                                                  ushort_t* __restrict__ Xl,
                                                  ushort_t* __restrict__ XTH,
                                                  int N) {
    int chunk = blockIdx.x;
    int t = threadIdx.x;
    __shared__ float xsh[32][33];
    int s = t >> 3, q = t & 7;
    int n = chunk * 32 + s;
    float4 v = make_float4(0.f, 0.f, 0.f, 0.f);
    if (n < N) v = ((const float4*)(X + (size_t)n * 32))[q];
    float vv[4] = { v.x, v.y, v.z, v.w };
    xsh[s][q * 4 + 0] = v.x; xsh[s][q * 4 + 1] = v.y;
    xsh[s][q * 4 + 2] = v.z; xsh[s][q * 4 + 3] = v.w;
    if (n < N) {
        ushort_t h[4], l[4];
#pragma unroll
        for (int i = 0; i < 4; ++i) {
            h[i] = f2bf(vv[i]);
            l[i] = f2bf(vv[i] - bf2f(h[i]));
        }
        size_t o = (size_t)n * 32 + q * 4;
        *(uint2*)(Xh + o) = make_uint2((uint_t)h[0] | ((uint_t)h[1] << 16),
                                       (uint_t)h[2] | ((uint_t)h[3] << 16));
        *(uint2*)(Xl + o) = make_uint2((uint_t)l[0] | ((uint_t)l[1] << 16),
                                       (uint_t)l[2] | ((uint_t)l[3] << 16));
    }
    __syncthreads();
    int di = t >> 7;
    int lane = (t >> 1) & 63;
    int jj0 = (t & 1) * 4;
    int c = lane & 15, quad = lane >> 4;
    int d = di * 16 + c;
    ushort_t fh[4];
#pragma unroll
    for (int i = 0; i < 4; ++i) fh[i] = f2bf(xsh[quad * 8 + jj0 + i][d]);
    size_t fo = ((size_t)(chunk * 2 + di) * 64 + lane) * 8 + jj0;
    *(uint2*)(XTH + fo) = make_uint2((uint_t)fh[0] | ((uint_t)fh[1] << 16),
                                     (uint_t)fh[2] | ((uint_t)fh[3] << 16));
}

// ---------------- prep0: reads raw inputs, emits W/Bv/Cc ----
__global__ __launch_bounds__(64) void gmm_prep0(const float* __restrict__ w,
                                                const float* __restrict__ mu,
                                                const float* __restrict__ cov,
                                                ushort_t* __restrict__ Wh,
                                                ushort_t* __restrict__ Wl,
                                                float* __restrict__ Bv,
                                                float* __restrict__ Cc) {
    int k = blockIdx.x;
    int t = threadIdx.x;
    __shared__ float L[32][33];
    __shared__ float Ai[32][33];
    const float* cv = cov + (size_t)k * 1024;
    const float* muk = mu + (size_t)k * 32;
#pragma unroll
    for (int rep = 0; rep < 16; ++rep) {
        int idx = rep * 64 + t;
        int i = idx >> 5, j = idx & 31;
        L[i][j] = cv[idx] + (i == j ? REGC : 0.f);
    }
    __syncthreads();
#pragma unroll
    for (int j = 0; j < 32; ++j) {
        float s = L[j][j];
#pragma unroll
        for (int p = 0; p < j; ++p) { float v = L[j][p]; s -= v * v; }
        float dj = sqrtf(s);
        if (t > j && t < 32) {
            float s2 = L[t][j];
#pragma unroll
            for (int p = 0; p < j; ++p) s2 -= L[t][p] * L[j][p];
            L[t][j] = s2 / dj;
        }
        if (t == j) L[j][j] = dj;
        __syncthreads();
    }
    if (t < 32) {
        float ai[32];
#pragma unroll
        for (int r = 0; r < 32; ++r) {
            float s = (r == t) ? 1.f : 0.f;
#pragma unroll
            for (int p = 0; p < r; ++p) s -= L[r][p] * ai[p];
            ai[r] = s / L[r][r];
        }
#pragma unroll
        for (int r = 0; r < 32; ++r) Ai[r][t] = ai[r];
    }
    __syncthreads();
#pragma unroll
    for (int rep = 0; rep < 16; ++rep) {
        int idx = rep * 64 + t;
        int i = idx >> 5, j = idx & 31;
        float v = Ai[i][j];
        ushort_t h = f2bf(v);
        Wh[(size_t)(k * 32 + i) * 32 + j] = h;
        Wl[(size_t)(k * 32 + i) * 32 + j] = f2bf(v - bf2f(h));
    }
    if (t < 32) {
        float s = 0.f;
#pragma unroll
        for (int j = 0; j < 32; ++j) s += Ai[t][j] * muk[j];
        Bv[k * 32 + t] = s;
    }
    float wsum = 0.f;
#pragma unroll
    for (int i = 0; i < 16; ++i) wsum += w[i];
    float lv = (t < 32) ? logf(L[t & 31][t & 31]) : 0.f;
#pragma unroll
    for (int off = 1; off < 32; off <<= 1) lv += __shfl_xor(lv, off);
    if (t == 0) Cc[k] = logf(w[k] / wsum) - 0.5f * 32.0f * LOG2PI - lv;
}

// ---------------- fused estep+moment (R10 structure, cheap pack) -------------
__global__ __launch_bounds__(1024) __attribute__((amdgpu_waves_per_eu(4, 4)))
void gmm_emstep(const ushort_t* __restrict__ Xh, const ushort_t* __restrict__ Xl,
                const ushort_t* __restrict__ XTH,
                const ushort_t* __restrict__ Wh, const ushort_t* __restrict__ Wl,
                const float* __restrict__ Bv, const float* __restrict__ Cc,
                float* __restrict__ part, int N) {
    __shared__ float rsh[16][516];
    int t = threadIdx.x;
    int wave = t >> 6, lane = t & 63;
    int quad = lane >> 4, c = lane & 15;

    int wstart0 = (int)blockIdx.x * 512 + wave * 32;
    bool dup = (wstart0 + 32 > N);
    int wst = dup ? ((N >= 32) ? N - 32 : 0) : wstart0;

    size_t xo0 = (size_t)(wst + c) * 32 + quad * 8;
    size_t xo1 = (size_t)(wst + 16 + c) * 32 + quad * 8;
    short8 ah0 = *(const short8*)(Xh + xo0);
    short8 al0 = *(const short8*)(Xl + xo0);
    short8 ah1 = *(const short8*)(Xh + xo1);
    short8 al1 = *(const short8*)(Xl + xo1);

    // ---- phase 1: estep (R4-R10-validated) ----
    {
        f32x4 p0[2], p1[2], p2[2], p3[2], fin[2];
#pragma unroll
        for (int k = 0; k < 16; ++k) {
            size_t w0 = (size_t)(k * 32 + c) * 32 + quad * 8;
            size_t w1 = w0 + 512;
            short8 bh0 = *(const short8*)(Wh + w0);
            short8 bl0 = *(const short8*)(Wl + w0);
            short8 bh1 = *(const short8*)(Wh + w1);
            short8 bl1 = *(const short8*)(Wl + w1);
            float bv0 = Bv[k * 32 + c];
            float bv1 = Bv[k * 32 + 16 + c];
#pragma unroll
            for (int tt = 0; tt < 2; ++tt) {
                short8 ah = tt ? ah1 : ah0;
                short8 al = tt ? al1 : al0;
                f32x4 a0 = {0.f, 0.f, 0.f, 0.f};
                f32x4 a1 = {0.f, 0.f, 0.f, 0.f};
                a0 = __builtin_amdgcn_mfma_f32_16x16x32_bf16(ah, bh0, a0, 0, 0, 0);
                a0 = __builtin_amdgcn_mfma_f32_16x16x32_bf16(ah, bl0, a0, 0, 0, 0);
                a0 = __builtin_amdgcn_mfma_f32_16x16x32_bf16(al, bh0, a0, 0, 0, 0);
                a1 = __builtin_amdgcn_mfma_f32_16x16x32_bf16(ah, bh1, a1, 0, 0, 0);
                a1 = __builtin_amdgcn_mfma_f32_16x16x32_bf16(ah, bl1, a1, 0, 0, 0);
                a1 = __builtin_amdgcn_mfma_f32_16x16x32_bf16(al, bh1, a1, 0, 0, 0);
                f32x4 ms;
#pragma unroll
                for (int r = 0; r < 4; ++r) {
                    float d0 = a0[r] - bv0;
                    float d1 = a1[r] - bv1;
                    ms[r] = fmaf(d0, d0, d1 * d1);
                }
                if ((k & 1) == 0) { p0[tt] = ms; }
                else {
                    f32x4 a = p0[tt] + shx4(p0[tt], 1);
                    f32x4 b = ms + shx4(ms, 1);
                    f32x4 v = sel4((c & 1) != 0, b, a);
                    if ((k & 2) == 0) { p1[tt] = v; }
                    else {
                        a = p1[tt] + shx4(p1[tt], 2); b = v + shx4(v, 2); v = sel4((c & 2) != 0, b, a);
                        if ((k & 4) == 0) { p2[tt] = v; }
                        else {
                            a = p2[tt] + shx4(p2[tt], 4); b = v + shx4(v, 4); v = sel4((c & 4) != 0, b, a);
                            if ((k & 8) == 0) { p3[tt] = v; }
                            else {
                                a = p3[tt] + shx4(p3[tt], 8); b = v + shx4(v, 8);
                                fin[tt] = sel4((c & 8) != 0, b, a);
                            }
                        }
                    }
                }
            }
        }
        float ccv = Cc[c];
#pragma unroll
        for (int tt = 0; tt < 2; ++tt) {
            f32x4 lp;
#pragma unroll
            for (int r = 0; r < 4; ++r) lp[r] = ccv - 0.5f * fin[tt][r];
            f32x4 mx = lp;
#pragma unroll
            for (int off = 1; off < 16; off <<= 1) {
                f32x4 s = shx4(mx, off);
#pragma unroll
                for (int r = 0; r < 4; ++r) mx[r] = fmaxf(mx[r], s[r]);
            }
            f32x4 e;
#pragma unroll
            for (int r = 0; r < 4; ++r) e[r] = __expf(lp[r] - mx[r]);
            f32x4 sm = e;
#pragma unroll
            for (int off = 1; off < 16; off <<= 1) sm = sm + shx4(sm, off);
            f32x4 sv;
#pragma unroll
            for (int r = 0; r < 4; ++r) sv[r] = dup ? 0.f : e[r] / sm[r];
            *(f32x4*)&rsh[c][wave * 32 + tt * 16 + quad * 4] = sv;
        }
    }
    __syncthreads();

    // ---- phase 2: moment (wave = component, block's own 16 chunks, cheap pack) ----
    {
        int k = wave;
        f32x4 m00 = {0.f,0.f,0.f,0.f}, m01 = {0.f,0.f,0.f,0.f};
        f32x4 m10 = {0.f,0.f,0.f,0.f}, m11 = {0.f,0.f,0.f,0.f};
        float row0 = 0.f, row1 = 0.f, corner = 0.f;
#pragma unroll 4
        for (int ch = 0; ch < 16; ++ch) {
            size_t fb = (((size_t)((int)blockIdx.x * 16 + ch)) * 128 + lane) * 8;
            short8 bh0 = *(const short8*)(XTH + fb);
            short8 bh1 = *(const short8*)(XTH + fb + 512);
            float r8[8];
#pragma unroll
            for (int jj = 0; jj < 8; ++jj) r8[jj] = rsh[k][ch * 32 + quad * 8 + jj];
            corner += ((r8[0]+r8[1])+(r8[2]+r8[3])) + ((r8[4]+r8[5])+(r8[6]+r8[7]));
            short8 a0 = pack_rx(r8, bh0, row0);
            short8 a1 = pack_rx(r8, bh1, row1);
            m00 = __builtin_amdgcn_mfma_f32_16x16x32_bf16(a0, bh0, m00, 0, 0, 0);
            m01 = __builtin_amdgcn_mfma_f32_16x16x32_bf16(a0, bh1, m01, 0, 0, 0);
            m10 = __builtin_amdgcn_mfma_f32_16x16x32_bf16(a1, bh0, m10, 0, 0, 0);
            m11 = __builtin_amdgcn_mfma_f32_16x16x32_bf16(a1, bh1, m11, 0, 0, 0);
        }
        row0 += __shfl_xor(row0, 16);  row0 += __shfl_xor(row0, 32);
        row1 += __shfl_xor(row1, 16);  row1 += __shfl_xor(row1, 32);
        corner += __shfl_xor(corner, 16);  corner += __shfl_xor(corner, 32);

        float* pb = part + ((size_t)blockIdx.x * 16 + k) * PART_K;
#pragma unroll
        for (int r = 0; r < 4; ++r) {
            pb[(quad * 4 + r) * 34 + c]           = m00[r];
            pb[(quad * 4 + r) * 34 + 16 + c]      = m01[r];
            pb[(16 + quad * 4 + r) * 34 + c]      = m10[r];
            pb[(16 + quad * 4 + r) * 34 + 16 + c] = m11[r];
        }
        if (quad == 0) {
            pb[32 * 34 + c]      = row0;
            pb[32 * 34 + 16 + c] = row1;
        }
        if (lane == 0) pb[32 * 34 + 32] = corner;
    }
}

// ---------------- reduce stage 1: npart partials -> RS slices (coalesced) ----------
__global__ __launch_bounds__(256) void gmm_reduce1(const float* __restrict__ part,
                                                   float* __restrict__ part2,
                                                   int npart) {
    int k = blockIdx.x, g = blockIdx.y;
    int nb = (npart + RS - 1) / RS;
    int b0 = g * nb;
    int b1 = b0 + nb; if (b1 > npart) b1 = npart;
    for (int idx = threadIdx.x; idx < PART_K; idx += 256) {
        float s = 0.f;
#pragma unroll 4
        for (int b = b0; b < b1; ++b)
            s += part[((size_t)b * 16 + k) * PART_K + idx];
        part2[((size_t)g * 16 + k) * PART_K + idx] = s;
    }
}

// ---------------- reduce stage 2 + finalize + prep (16 slices only) ---------
__global__ __launch_bounds__(1024) void gmm_redfin_prep(const float* __restrict__ part2,
                                                        ushort_t* __restrict__ Wh,
                                                        ushort_t* __restrict__ Wl,
                                                        float* __restrict__ Bv,
                                                        float* __restrict__ Cc,
                                                        int N) {
    int k = blockIdx.x;
    int t = threadIdx.x;
    __shared__ float S[1156];
    __shared__ float L[1056];     // 32x33
    __shared__ float Ai[1056];
    __shared__ float mean[32];

    for (int idx = t; idx < 1121; idx += 1024) {
        float s = 0.f;
#pragma unroll
        for (int b = 0; b < RS; ++b)
            s += part2[((size_t)b * 16 + k) * PART_K + idx];
        S[idx] = s;
    }
    __syncthreads();
    float nk = S[32 * 34 + 32] + RESP_EPS;
    float inv = 1.f / nk;
    {
        int i = t >> 5, j = t & 31;
        float mi = S[32 * 34 + i] * inv;
        float mj = S[32 * 34 + j] * inv;
        // M-step REGC + log_gauss REGC (reference applies both)
        L[i * 33 + j] = S[i * 34 + j] * inv - mi * mj + ((i == j) ? 2.f * REGC : 0.f);
    }
    if (t < 32) mean[t] = S[32 * 34 + t] * inv;
    __syncthreads();

#pragma unroll
    for (int j = 0; j < 32; ++j) {
        if (t < 32) {
            float s = L[j * 33 + j];
#pragma unroll
            for (int p = 0; p < j; ++p) { float v = L[j * 33 + p]; s -= v * v; }
            float dj = sqrtf(s);
            if (t > j) {
                float s2 = L[t * 33 + j];
#pragma unroll
                for (int p = 0; p < j; ++p) s2 -= L[t * 33 + p] * L[j * 33 + p];
                L[t * 33 + j] = s2 / dj;
            }
            if (t == j) L[j * 33 + j] = dj;
        }
        __syncthreads();
    }
    if (t < 32) {
        float ai[32];
#pragma unroll
        for (int r = 0; r < 32; ++r) {
            float s = (r == t) ? 1.f : 0.f;
#pragma unroll
            for (int p = 0; p < r; ++p) s -= L[r * 33 + p] * ai[p];
            ai[r] = s / L[r * 33 + r];
        }
#pragma unroll
        for (int r = 0; r < 32; ++r) Ai[r * 33 + t] = ai[r];
    }
    __syncthreads();
    {
        int i = t >> 5, j = t & 31;
        float v = Ai[i * 33 + j];
        ushort_t h = f2bf(v);
        Wh[(size_t)(k * 32 + i) * 32 + j] = h;
        Wl[(size_t)(k * 32 + i) * 32 + j] = f2bf(v - bf2f(h));
    }
    if (t < 32) {
        float s = 0.f;
#pragma unroll
        for (int j = 0; j < 32; ++j) s += Ai[t * 33 + j] * mean[j];
        Bv[k * 32 + t] = s;
    }
    float lv = (t < 32) ? logf(L[(t & 31) * 33 + (t & 31)]) : 0.f;
#pragma unroll
    for (int off = 1; off < 32; off <<= 1) lv += __shfl_xor(lv, off);
    if (t == 0) Cc[k] = logf(nk / (float)N) - 0.5f * 32.0f * LOG2PI - lv;
}

// ---------------- final estep: log-likelihood only ----------------
__global__ __launch_bounds__(256, 2) void gmm_estep_fin(const ushort_t* __restrict__ Xh,
                                                        const ushort_t* __restrict__ Xl,
                                                        const ushort_t* __restrict__ Wh,
                                                        const ushort_t* __restrict__ Wl,
                                                        const float* __restrict__ Bv,
                                                        const float* __restrict__ Cc,
                                                        float* __restrict__ out,
                                                        int N) {
    int t = threadIdx.x;
    int wave = t >> 6, lane = t & 63;
    int quad = lane >> 4, c = lane & 15;
    int wstart = (blockIdx.x * 4 + wave) * 32;
    if (wstart + 32 > N) wstart = (N >= 32) ? (N - 32) : 0;
    bool al4 = ((N & 3) == 0);

    size_t xo0 = (size_t)(wstart + c) * 32 + quad * 8;
    size_t xo1 = (size_t)(wstart + 16 + c) * 32 + quad * 8;
    short8 ah0 = *(const short8*)(Xh + xo0);
    short8 al0 = *(const short8*)(Xl + xo0);
    short8 ah1 = *(const short8*)(Xh + xo1);
    short8 al1 = *(const short8*)(Xl + xo1);

    f32x4 p0[2], p1[2], p2[2], p3[2], fin[2];
#pragma unroll
    for (int k = 0; k < 16; ++k) {
        size_t w0 = (size_t)(k * 32 + c) * 32 + quad * 8;
        size_t w1 = w0 + 512;
        short8 bh0 = *(const short8*)(Wh + w0);
        short8 bl0 = *(const short8*)(Wl + w0);
        short8 bh1 = *(const short8*)(Wh + w1);
        short8 bl1 = *(const short8*)(Wl + w1);
        float bv0 = Bv[k * 32 + c];
        float bv1 = Bv[k * 32 + 16 + c];
#pragma unroll
        for (int tt = 0; tt < 2; ++tt) {
            short8 ah = tt ? ah1 : ah0;
            short8 al = tt ? al1 : al0;
            f32x4 a0 = {0.f, 0.f, 0.f, 0.f};
            f32x4 a1 = {0.f, 0.f, 0.f, 0.f};
            a0 = __builtin_amdgcn_mfma_f32_16x16x32_bf16(ah, bh0, a0, 0, 0, 0);
            a0 = __builtin_amdgcn_mfma_f32_16x16x32_bf16(ah, bl0, a0, 0, 0, 0);
            a0 = __builtin_amdgcn_mfma_f32_16x16x32_bf16(al, bh0, a0, 0, 0, 0);
            a1 = __builtin_amdgcn_mfma_f32_16x16x32_bf16(ah, bh1, a1, 0, 0, 0);
            a1 = __builtin_amdgcn_mfma_f32_16x16x32_bf16(ah, bl1, a1, 0, 0, 0);
            a1 = __builtin_amdgcn_mfma_f32_16x16x32_bf16(al, bh1, a1, 0, 0, 0);
            f32x4 ms;
#pragma unroll
            for (int r = 0; r < 4; ++r) {
                float d0 = a0[r] - bv0;
                float d1 = a1[r] - bv1;
                ms[r] = fmaf(d0, d0, d1 * d1);
            }
            if ((k & 1) == 0) { p0[tt] = ms; }
            else {
                f32x4 a = p0[tt] + shx4(p0[tt], 1);
                f32x4 b = ms + shx4(ms, 1);
                f32x4 v = sel4((c & 1) != 0, b, a);
                if ((k & 2) == 0) { p1[tt] = v; }
                else {
                    a = p1[tt] + shx4(p1[tt], 2); b = v + shx4(v, 2); v = sel4((c & 2) != 0, b, a);
                    if ((k & 4) == 0) { p2[tt] = v; }
                    else {
                        a = p2[tt] + shx4(p2[tt], 4); b = v + shx4(v, 4); v = sel4((c & 4) != 0, b, a);
                        if ((k & 8) == 0) { p3[tt] = v; }
                        else {
                            a = p3[tt] + shx4(p3[tt], 8); b = v + shx4(v, 8);
                            fin[tt] = sel4((c & 8) != 0, b, a);
                        }
                    }
                }
            }
        }
    }
    float ccv = Cc[c];
#pragma unroll
    for (int tt = 0; tt < 2; ++tt) {
        f32x4 lp;
#pragma unroll
        for (int r = 0; r < 4; ++r) lp[r] = ccv - 0.5f * fin[tt][r];
        f32x4 mx = lp;
#pragma unroll
        for (int off = 1; off < 16; off <<= 1) {
            f32x4 s = shx4(mx, off);
#pragma unroll
            for (int r = 0; r < 4; ++r) mx[r] = fmaxf(mx[r], s[r]);
        }
        f32x4 e;
#pragma unroll
        for (int r = 0; r < 4; ++r) e[r] = __expf(lp[r] - mx[r]);
        f32x4 sm = e;
#pragma unroll
        for (int off = 1; off < 16; off <<= 1) sm = sm + shx4(sm, off);
        if (c == 0) {
            int nb = wstart + tt * 16 + quad * 4;
            f32x4 o;
#pragma unroll
            for (int r = 0; r < 4; ++r) o[r] = mx[r] + __logf(sm[r]);
            if (al4) *(f32x4*)(out + nb) = o;
            else { for (int r = 0; r < 4; ++r) out[nb + r] = o[r]; }
        }
    }
}

// ================================== launcher ==================================
extern "C" void kernel_launch(void* const* d_in, const int* in_sizes, int n_in,
                              void* d_out, int out_size, void* d_ws, size_t ws_size,
                              hipStream_t stream) {
    const float* X   = (const float*)d_in[0];
    const float* w   = (const float*)d_in[1];
    const float* mu  = (const float*)d_in[2];
    const float* cov = (const float*)d_in[3];
    const int NITER = 5;
    int N = in_sizes[0] / 32;
    int NB = (N + 511) / 512;        // emstep blocks (512 samples each)
    int NCB = NB * 16;               // staged chunks (zero-padded past N)

    float* ws = (float*)d_ws;
    float*    Bv = ws;                               // 512
    float*    Cc = ws + 512;                         // 16 (+pad to 528)
    ushort_t* Wh = (ushort_t*)(ws + 528);            // 8192 f
    ushort_t* Wl = (ushort_t*)(ws + 8720);           // 8192 f -> 16912
    ushort_t* Xh = (ushort_t*)(ws + 16912);          // 16N f
    ushort_t* Xl = (ushort_t*)(ws + 16912 + (size_t)16 * N);
    size_t xt0 = 16912 + (size_t)32 * N;
    size_t SZ  = (size_t)NCB * 512;                  // XTH floats
    ushort_t* XTH = (ushort_t*)(ws + xt0);
    float*  part2 = ws + xt0 + SZ;                   // RS*16*PART_K floats
    float*  part  = part2 + (size_t)RS * 16 * PART_K;   // NB*16*PART_K floats

    float* out = (float*)d_out;

    int eblocks = ((N + 31) / 32 + 3) / 4;

    gmm_xsplit<<<NCB, 256, 0, stream>>>(X, Xh, Xl, XTH, N);
    gmm_prep0<<<16, 64, 0, stream>>>(w, mu, cov, Wh, Wl, Bv, Cc);

    for (int it = 0; it < NITER; ++it) {
        gmm_emstep<<<NB, 1024, 0, stream>>>(Xh, Xl, XTH, Wh, Wl, Bv, Cc, part, N);
        dim3 r1(16, RS);
        gmm_reduce1<<<r1, 256, 0, stream>>>(part, part2, NB);
        gmm_redfin_prep<<<16, 1024, 0, stream>>>(part2, Wh, Wl, Bv, Cc, N);
    }
    gmm_estep_fin<<<eblocks, 256, 0, stream>>>(Xh, Xl, Wh, Wl, Bv, Cc, out, N);
}